// Round 1
// baseline (9337.715 us; speedup 1.0000x reference)
//
#include <hip/hip_runtime.h>
#include <math.h>

// ---- problem constants ----
#define NNODES   20000
#define NEDGES   320000
#define NGRAPHS  100
#define CC       64        // LATENT
#define NBASIS   8
#define FLATDIM  576       // C*(1+3+5)
#define IRRDIM   25
#define NRADII   64
#define POSIN    640       // FLAT + C
#define POSOUT   1600      // NRADII*IRRDIM

__device__ __forceinline__ float silu_f(float x){ return x / (1.0f + __expf(-x)); }
__device__ __forceinline__ float sigm_f(float x){ return 1.0f / (1.0f + __expf(-x)); }

// ---- prep: transpose radial_w1 [8][64]->[64][8], radial_w3 [64][192]->[192][64],
//      and mark first node of each graph ----
__global__ void prep_kernel(const float* __restrict__ w1, const float* __restrict__ w3,
                            const int* __restrict__ n_node,
                            float* __restrict__ w1t, float* __restrict__ w3t,
                            int* __restrict__ flags)
{
    int tid = blockIdx.x * blockDim.x + threadIdx.x;
    int stride = gridDim.x * blockDim.x;
    for (int i = tid; i < 8 * 64; i += stride) {
        int b = i / 64, k = i % 64;
        w1t[k * 8 + b] = w1[i];
    }
    for (int i = tid; i < 64 * 192; i += stride) {
        int k = i / 192, o = i % 192;
        w3t[o * 64 + k] = w3[i];
    }
    if (blockIdx.x == 0 && threadIdx.x == 0) {
        int a = 0;
        for (int g = 0; g < NGRAPHS; g++) { flags[a] = g + 1; a += n_node[g]; }
    }
}

// ---- edge stage: one thread per edge. Weight reads are wave-uniform (scalar loads).
// hid1 recomputed per-k so no runtime-indexed register array exists. ----
__global__ __launch_bounds__(256) void edge_kernel(
    const float* __restrict__ pos, const int* __restrict__ species,
    const int* __restrict__ senders, const int* __restrict__ receivers,
    const float* __restrict__ node_embed,
    const float* __restrict__ w1t, const float* __restrict__ w2,
    const float* __restrict__ w3t, float* __restrict__ acc)
{
    int e = blockIdx.x * blockDim.x + threadIdx.x;
    if (e >= NEDGES) return;
    int snd = senders[e];
    int rcv = receivers[e];

    float dx = pos[rcv * 3 + 0] - pos[snd * 3 + 0];
    float dy = pos[rcv * 3 + 1] - pos[snd * 3 + 1];
    float dz = pos[rcv * 3 + 2] - pos[snd * 3 + 2];
    float r = sqrtf(dx * dx + dy * dy + dz * dz);
    float rinv = 1.0f / (r + 1e-9f);
    float ux = dx * rinv, uy = dy * rinv, uz = dz * rinv;

    const float SQ3 = 1.7320508075688772f;
    const float S15 = 3.872983346207417f;
    const float S5  = 2.2360679774997896f;
    float sh[8];
    sh[0] = SQ3 * ux; sh[1] = SQ3 * uy; sh[2] = SQ3 * uz;
    sh[3] = S15 * ux * uy;
    sh[4] = S15 * uy * uz;
    sh[5] = 0.5f * S5 * (3.0f * uz * uz - 1.0f);
    sh[6] = S15 * ux * uz;
    sh[7] = 0.5f * S15 * (ux * ux - uy * uy);

    const float PI = 3.14159265358979323846f;
    float rc = r * 0.2f;                       // r / R_CUT
    float env = 0.5f * (__cosf(PI * fminf(rc, 1.0f)) + 1.0f);
    float scale = 0.6324555320336759f * rinv * env;   // sqrt(2/R_CUT)/(r+eps)*env
    float rb[8];
    #pragma unroll
    for (int b = 0; b < 8; b++) rb[b] = scale * __sinf((float)(b + 1) * PI * rc);

    // stage 2: hid2[c] = silu( sum_k silu(rb . w1[:,k]) * w2[k][c] )
    float hid2[64];
    #pragma unroll
    for (int c = 0; c < 64; c++) hid2[c] = 0.0f;
    for (int k = 0; k < 64; k++) {
        float a = 0.0f;
        const float* w1c = w1t + k * 8;
        #pragma unroll
        for (int b = 0; b < 8; b++) a += rb[b] * w1c[b];
        float h1 = silu_f(a);
        const float* w2row = w2 + k * 64;
        #pragma unroll
        for (int c = 0; c < 64; c++) hid2[c] += h1 * w2row[c];
    }
    #pragma unroll
    for (int c = 0; c < 64; c++) hid2[c] = silu_f(hid2[c]);

    int sp = species[snd];
    const float* hrow = node_embed + sp * 64;
    float* abase = acc + (size_t)rcv * FLATDIM;

    // stage 3: wts = hid2 @ w3 (via transposed w3t), then messages + scatter.
    // inv = 1/sqrt(16) = 0.25 folded into the message.
    for (int c = 0; c < 64; c++) {
        const float* p0 = w3t + (c) * 64;
        const float* p1 = w3t + (64 + c) * 64;
        const float* p2 = w3t + (128 + c) * 64;
        float a0 = 0.0f, a1 = 0.0f, a2 = 0.0f;
        #pragma unroll
        for (int k = 0; k < 64; k++) {
            float h = hid2[k];
            a0 += h * p0[k];
            a1 += h * p1[k];
            a2 += h * p2[k];
        }
        float hsc = hrow[c];
        float b0 = a0 * hsc * 0.25f;
        float b1 = a1 * hsc * 0.25f;
        float b2 = a2 * hsc * 0.25f;
        atomicAdd(abase + c, b0);
        #pragma unroll
        for (int m = 0; m < 3; m++) atomicAdd(abase + (1 + m) * 64 + c, b1 * sh[m]);
        #pragma unroll
        for (int m = 0; m < 5; m++) atomicAdd(abase + (4 + m) * 64 + c, b2 * sh[3 + m]);
    }
}

// ---- node stage: one wave per node, lane = output channel d ----
__global__ __launch_bounds__(64) void node_kernel(
    const float* __restrict__ acc, const int* __restrict__ species,
    const float* __restrict__ node_embed,
    const float* __restrict__ lin_w0, const float* __restrict__ lin_w1,
    const float* __restrict__ lin_w2, const float* __restrict__ skip_w,
    const float* __restrict__ gate_w, const float* __restrict__ focus_w,
    const float* __restrict__ focus_b, const int* __restrict__ flags,
    float* __restrict__ out_focus, float* __restrict__ focus_emb)
{
    int n = blockIdx.x;
    int lane = threadIdx.x;
    __shared__ float sa[9][64];
    __shared__ float hh[64];
    __shared__ float ss[64];

    const float* arow = acc + (size_t)n * FLATDIM;
    #pragma unroll
    for (int j = 0; j < 9; j++) sa[j][lane] = arow[j * 64 + lane];
    int sp = species[n];
    hh[lane] = node_embed[sp * 64 + lane];
    __syncthreads();

    // s[d] = a0 . lin_w0[:,d] + h . skip_w[sp][:,d]
    float s = 0.0f;
    const float* skipb = skip_w + sp * 4096;
    for (int c = 0; c < 64; c++)
        s += sa[0][c] * lin_w0[c * 64 + lane] + hh[c] * skipb[c * 64 + lane];

    // v[d][m], t[d][m]
    float v0 = 0, v1 = 0, v2 = 0, t0 = 0, t1 = 0, t2 = 0, t3 = 0, t4 = 0;
    for (int c = 0; c < 64; c++) {
        float wa = lin_w1[c * 64 + lane];
        v0 += sa[1][c] * wa; v1 += sa[2][c] * wa; v2 += sa[3][c] * wa;
        float wb = lin_w2[c * 64 + lane];
        t0 += sa[4][c] * wb; t1 += sa[5][c] * wb; t2 += sa[6][c] * wb;
        t3 += sa[7][c] * wb; t4 += sa[8][c] * wb;
    }

    ss[lane] = s;
    __syncthreads();
    float g1a = 0.0f, g2a = 0.0f;
    for (int c = 0; c < 64; c++) {
        float sc = ss[c];
        g1a += sc * gate_w[c * 128 + lane];
        g2a += sc * gate_w[c * 128 + 64 + lane];
    }
    float g1 = sigm_f(g1a), g2 = sigm_f(g2a);
    float s_out = s * sigm_f(s);
    float vo0 = v0 * g1, vo1 = v1 * g1, vo2 = v2 * g1;
    float to0 = t0 * g2, to1 = t1 * g2, to2 = t2 * g2, to3 = t3 * g2, to4 = t4 * g2;

    // focus logit: emb . focus_w  (emb = [s_out | v.reshape | t.reshape])
    float p = s_out * focus_w[lane]
            + vo0 * focus_w[64 + lane * 3 + 0]
            + vo1 * focus_w[64 + lane * 3 + 1]
            + vo2 * focus_w[64 + lane * 3 + 2]
            + to0 * focus_w[256 + lane * 5 + 0]
            + to1 * focus_w[256 + lane * 5 + 1]
            + to2 * focus_w[256 + lane * 5 + 2]
            + to3 * focus_w[256 + lane * 5 + 3]
            + to4 * focus_w[256 + lane * 5 + 4];
    #pragma unroll
    for (int off = 32; off > 0; off >>= 1) p += __shfl_down(p, off);
    if (lane == 0) out_focus[n] = p + focus_b[0];

    int fg = flags[n];
    if (fg) {
        float* fe = focus_emb + (size_t)(fg - 1) * FLATDIM;
        fe[lane] = s_out;
        fe[64 + lane * 3 + 0] = vo0;
        fe[64 + lane * 3 + 1] = vo1;
        fe[64 + lane * 3 + 2] = vo2;
        fe[256 + lane * 5 + 0] = to0;
        fe[256 + lane * 5 + 1] = to1;
        fe[256 + lane * 5 + 2] = to2;
        fe[256 + lane * 5 + 3] = to3;
        fe[256 + lane * 5 + 4] = to4;
    }
}

// ---- graph stage: block per graph ----
__global__ __launch_bounds__(256) void graph_kernel(
    const float* __restrict__ focus_emb, const int* __restrict__ target_species,
    const float* __restrict__ species_embed,
    const float* __restrict__ species_w, const float* __restrict__ species_b,
    const float* __restrict__ pos_w, const float* __restrict__ pos_b,
    float* __restrict__ out_species, float* __restrict__ out_pos)
{
    int g = blockIdx.x;
    int tid = threadIdx.x;
    __shared__ float pin[POSIN];
    const float* fe = focus_emb + (size_t)g * FLATDIM;
    for (int i = tid; i < FLATDIM; i += 256) pin[i] = fe[i];
    int tsp = target_species[g];
    if (tid < CC) pin[FLATDIM + tid] = species_embed[tsp * CC + tid];
    __syncthreads();

    if (tid < 5) {
        float a = species_b[tid];
        for (int k = 0; k < FLATDIM; k++) a += pin[k] * species_w[k * 5 + tid];
        out_species[g * 5 + tid] = a;
    }
    for (int o = tid; o < POSOUT; o += 256) {
        float a = pos_b[o];
        for (int k = 0; k < POSIN; k++) a += pin[k] * pos_w[(size_t)k * POSOUT + o];
        out_pos[(size_t)g * POSOUT + o] = a;
    }
}

extern "C" void kernel_launch(void* const* d_in, const int* in_sizes, int n_in,
                              void* d_out, int out_size, void* d_ws, size_t ws_size,
                              hipStream_t stream) {
    const float* positions      = (const float*)d_in[0];
    const int*   species        = (const int*)  d_in[1];
    const int*   senders        = (const int*)  d_in[2];
    const int*   receivers      = (const int*)  d_in[3];
    const int*   n_node         = (const int*)  d_in[4];
    const int*   target_species = (const int*)  d_in[5];
    const float* species_embed  = (const float*)d_in[6];
    const float* node_embed     = (const float*)d_in[7];
    const float* radial_w1      = (const float*)d_in[8];
    const float* radial_w2      = (const float*)d_in[9];
    const float* radial_w3      = (const float*)d_in[10];
    const float* lin_w0         = (const float*)d_in[11];
    const float* lin_w1         = (const float*)d_in[12];
    const float* lin_w2         = (const float*)d_in[13];
    const float* skip_w         = (const float*)d_in[14];
    const float* gate_w         = (const float*)d_in[15];
    const float* focus_w        = (const float*)d_in[16];
    const float* focus_b        = (const float*)d_in[17];
    const float* species_w      = (const float*)d_in[18];
    const float* species_b      = (const float*)d_in[19];
    const float* pos_w          = (const float*)d_in[20];
    const float* pos_b          = (const float*)d_in[21];

    // workspace layout (floats): acc[N*576] | flags[N] (int) | w1t[512] | w3t[12288] | focus_emb[100*576]
    float* ws        = (float*)d_ws;
    float* acc       = ws;
    int*   flags     = (int*)(ws + (size_t)NNODES * FLATDIM);
    float* w1t       = ws + (size_t)NNODES * FLATDIM + NNODES;
    float* w3t       = w1t + 512;
    float* focus_emb = w3t + 12288;

    // zero accumulator + flags (contiguous prefix)
    size_t zero_bytes = ((size_t)NNODES * FLATDIM + NNODES) * sizeof(float);
    hipMemsetAsync(d_ws, 0, zero_bytes, stream);

    prep_kernel<<<64, 256, 0, stream>>>(radial_w1, radial_w3, n_node, w1t, w3t, flags);

    edge_kernel<<<(NEDGES + 255) / 256, 256, 0, stream>>>(
        positions, species, senders, receivers, node_embed, w1t, radial_w2, w3t, acc);

    float* out       = (float*)d_out;
    float* out_focus = out;                 // [20000]
    float* out_spec  = out + NNODES;        // [100*5]
    float* out_pos   = out + NNODES + NGRAPHS * 5;  // [100*1600]

    node_kernel<<<NNODES, 64, 0, stream>>>(
        acc, species, node_embed, lin_w0, lin_w1, lin_w2, skip_w, gate_w,
        focus_w, focus_b, flags, out_focus, focus_emb);

    graph_kernel<<<NGRAPHS, 256, 0, stream>>>(
        focus_emb, target_species, species_embed, species_w, species_b,
        pos_w, pos_b, out_spec, out_pos);
}

// Round 2
// 1477.447 us; speedup vs baseline: 6.3202x; 6.3202x over previous
//
#include <hip/hip_runtime.h>
#include <math.h>

// ---- problem constants ----
#define NNODES   20000
#define NEDGES   320000
#define NGRAPHS  100
#define CC       64        // LATENT
#define FLATDIM  576       // C*(1+3+5)
#define POSIN    640       // FLAT + C
#define POSOUT   1600      // NRADII*IRRDIM
#define PAYLOAD  80        // hid2[64] + sh[8] + sp + pad -> 320B aligned

__device__ __forceinline__ float silu_f(float x){ return x / (1.0f + __expf(-x)); }
__device__ __forceinline__ float sigm_f(float x){ return 1.0f / (1.0f + __expf(-x)); }

// ---- prep: transpose radial_w1 [8][64]->[64][8]; graph-first flags; degree count ----
__global__ void prep_kernel(const float* __restrict__ w1, const int* __restrict__ n_node,
                            const int* __restrict__ receivers,
                            float* __restrict__ w1t, int* __restrict__ flags,
                            int* __restrict__ degree)
{
    int tid = blockIdx.x * blockDim.x + threadIdx.x;
    int stride = gridDim.x * blockDim.x;
    for (int i = tid; i < 8 * 64; i += stride) {
        int b = i / 64, k = i % 64;
        w1t[k * 8 + b] = w1[i];
    }
    for (int e = tid; e < NEDGES; e += stride)
        atomicAdd(&degree[receivers[e]], 1);
    if (tid == 0) {
        int a = 0;
        for (int g = 0; g < NGRAPHS; g++) { flags[a] = g + 1; a += n_node[g]; }
    }
}

// ---- exclusive scan of degree[20000] -> start[20001], single block ----
__global__ __launch_bounds__(1024) void scan_kernel(const int* __restrict__ degree,
                                                    int* __restrict__ start)
{
    __shared__ int partial[1024];
    int t = threadIdx.x;
    int base = t * 20;
    int s = 0;
    int loc[20];
    for (int i = 0; i < 20; i++) {
        int idx = base + i;
        int d = (idx < NNODES) ? degree[idx] : 0;
        loc[i] = s;
        s += d;
    }
    partial[t] = s;
    __syncthreads();
    if (t == 0) {
        int run = 0;
        for (int i = 0; i < 1024; i++) { int x = partial[i]; partial[i] = run; run += x; }
        start[NNODES] = run;   // = NEDGES
    }
    __syncthreads();
    int off = partial[t];
    for (int i = 0; i < 20; i++) {
        int idx = base + i;
        if (idx < NNODES) start[idx] = off + loc[i];
    }
}

// ---- edge stage: radial basis + sph + MLP stages 1-2; write compact payload;
//      fill CSR edge list slot ----
__global__ __launch_bounds__(256) void edge_kernel(
    const float* __restrict__ pos, const int* __restrict__ species,
    const int* __restrict__ senders, const int* __restrict__ receivers,
    const float* __restrict__ w1t, const float* __restrict__ w2,
    const int* __restrict__ start, int* __restrict__ cursor,
    int* __restrict__ edge_list, float* __restrict__ payload)
{
    int e = blockIdx.x * blockDim.x + threadIdx.x;
    if (e >= NEDGES) return;
    int snd = senders[e];
    int rcv = receivers[e];

    // CSR fill
    int slot = start[rcv] + atomicAdd(&cursor[rcv], 1);
    edge_list[slot] = e;

    float dx = pos[rcv * 3 + 0] - pos[snd * 3 + 0];
    float dy = pos[rcv * 3 + 1] - pos[snd * 3 + 1];
    float dz = pos[rcv * 3 + 2] - pos[snd * 3 + 2];
    float r = sqrtf(dx * dx + dy * dy + dz * dz);
    float rinv = 1.0f / (r + 1e-9f);
    float ux = dx * rinv, uy = dy * rinv, uz = dz * rinv;

    const float SQ3 = 1.7320508075688772f;
    const float S15 = 3.872983346207417f;
    const float S5  = 2.2360679774997896f;
    float sh[8];
    sh[0] = SQ3 * ux; sh[1] = SQ3 * uy; sh[2] = SQ3 * uz;
    sh[3] = S15 * ux * uy;
    sh[4] = S15 * uy * uz;
    sh[5] = 0.5f * S5 * (3.0f * uz * uz - 1.0f);
    sh[6] = S15 * ux * uz;
    sh[7] = 0.5f * S15 * (ux * ux - uy * uy);

    const float PI = 3.14159265358979323846f;
    float rc = r * 0.2f;
    float env = 0.5f * (__cosf(PI * fminf(rc, 1.0f)) + 1.0f);
    float scale = 0.6324555320336759f * rinv * env;
    float rb[8];
    #pragma unroll
    for (int b = 0; b < 8; b++) rb[b] = scale * __sinf((float)(b + 1) * PI * rc);

    float hid2[64];
    #pragma unroll
    for (int c = 0; c < 64; c++) hid2[c] = 0.0f;
    for (int k = 0; k < 64; k++) {
        float a = 0.0f;
        const float* w1c = w1t + k * 8;
        #pragma unroll
        for (int b = 0; b < 8; b++) a += rb[b] * w1c[b];
        float h1 = silu_f(a);
        const float* w2row = w2 + k * 64;
        #pragma unroll
        for (int c = 0; c < 64; c++) hid2[c] += h1 * w2row[c];
    }

    float* prow = payload + (size_t)e * PAYLOAD;
    #pragma unroll
    for (int q = 0; q < 16; q++) {
        float4 v = make_float4(silu_f(hid2[q * 4 + 0]), silu_f(hid2[q * 4 + 1]),
                               silu_f(hid2[q * 4 + 2]), silu_f(hid2[q * 4 + 3]));
        *reinterpret_cast<float4*>(prow + q * 4) = v;
    }
    *reinterpret_cast<float4*>(prow + 64) = make_float4(sh[0], sh[1], sh[2], sh[3]);
    *reinterpret_cast<float4*>(prow + 68) = make_float4(sh[4], sh[5], sh[6], sh[7]);
    prow[72] = (float)species[snd];
}

// ---- fused gather + node stage: one wave per node (4 waves/block) ----
__global__ __launch_bounds__(256) void node_kernel(
    const float* __restrict__ payload, const int* __restrict__ edge_list,
    const int* __restrict__ start,
    const int* __restrict__ species, const float* __restrict__ node_embed,
    const float* __restrict__ w3,            // radial_w3 original [64][192]
    const float* __restrict__ lin_w0, const float* __restrict__ lin_w1,
    const float* __restrict__ lin_w2, const float* __restrict__ skip_w,
    const float* __restrict__ gate_w, const float* __restrict__ focus_w,
    const float* __restrict__ focus_b, const int* __restrict__ flags,
    float* __restrict__ out_focus, float* __restrict__ focus_emb)
{
    int wave = threadIdx.x >> 6;
    int lane = threadIdx.x & 63;
    int n = blockIdx.x * 4 + wave;

    __shared__ float lds_h[4][64];
    __shared__ float sa[4][9][64];
    __shared__ float hh[4][64];
    __shared__ float ss[4][64];

    // ---- gather: aggregate messages over incident edges ----
    float a0 = 0, a1x = 0, a1y = 0, a1z = 0;
    float a2a = 0, a2b = 0, a2c = 0, a2d = 0, a2e = 0;
    int s0 = start[n], s1 = start[n + 1];
    for (int i = s0; i < s1; i++) {
        int e = edge_list[i];
        const float* p = payload + (size_t)e * PAYLOAD;
        float hval = p[lane];               // hid2[lane], coalesced
        float sh0 = p[64], sh1_ = p[65], sh2_ = p[66], sh3 = p[67];
        float sh4 = p[68], sh5 = p[69], sh6 = p[70], sh7 = p[71];
        int sp = (int)p[72];
        lds_h[wave][lane] = hval;
        float w0a = 0, w1a = 0, w2a = 0;
        #pragma unroll 8
        for (int k = 0; k < 64; k++) {
            float hk = lds_h[wave][k];       // broadcast
            const float* wr = w3 + k * 192;  // L1-resident 48KB
            w0a += hk * wr[lane];
            w1a += hk * wr[64 + lane];
            w2a += hk * wr[128 + lane];
        }
        float hs = node_embed[sp * 64 + lane];
        float b0 = w0a * hs, b1 = w1a * hs, b2 = w2a * hs;
        a0  += b0;
        a1x += b1 * sh0; a1y += b1 * sh1_; a1z += b1 * sh2_;
        a2a += b2 * sh3; a2b += b2 * sh4; a2c += b2 * sh5;
        a2d += b2 * sh6; a2e += b2 * sh7;
    }
    const float inv = 0.25f;   // 1/sqrt(16)
    a0 *= inv; a1x *= inv; a1y *= inv; a1z *= inv;
    a2a *= inv; a2b *= inv; a2c *= inv; a2d *= inv; a2e *= inv;

    // ---- node stage (wave-local LDS, no barriers needed) ----
    sa[wave][0][lane] = a0;
    sa[wave][1][lane] = a1x; sa[wave][2][lane] = a1y; sa[wave][3][lane] = a1z;
    sa[wave][4][lane] = a2a; sa[wave][5][lane] = a2b; sa[wave][6][lane] = a2c;
    sa[wave][7][lane] = a2d; sa[wave][8][lane] = a2e;
    int spn = species[n];
    hh[wave][lane] = node_embed[spn * 64 + lane];

    float s = 0.0f;
    const float* skipb = skip_w + spn * 4096;
    for (int c = 0; c < 64; c++)
        s += sa[wave][0][c] * lin_w0[c * 64 + lane] + hh[wave][c] * skipb[c * 64 + lane];

    float v0 = 0, v1 = 0, v2 = 0, t0 = 0, t1 = 0, t2 = 0, t3 = 0, t4 = 0;
    for (int c = 0; c < 64; c++) {
        float wa = lin_w1[c * 64 + lane];
        v0 += sa[wave][1][c] * wa; v1 += sa[wave][2][c] * wa; v2 += sa[wave][3][c] * wa;
        float wb = lin_w2[c * 64 + lane];
        t0 += sa[wave][4][c] * wb; t1 += sa[wave][5][c] * wb; t2 += sa[wave][6][c] * wb;
        t3 += sa[wave][7][c] * wb; t4 += sa[wave][8][c] * wb;
    }

    ss[wave][lane] = s;
    float g1a = 0.0f, g2a = 0.0f;
    for (int c = 0; c < 64; c++) {
        float sc = ss[wave][c];
        g1a += sc * gate_w[c * 128 + lane];
        g2a += sc * gate_w[c * 128 + 64 + lane];
    }
    float g1 = sigm_f(g1a), g2 = sigm_f(g2a);
    float s_out = s * sigm_f(s);
    float vo0 = v0 * g1, vo1 = v1 * g1, vo2 = v2 * g1;
    float to0 = t0 * g2, to1 = t1 * g2, to2 = t2 * g2, to3 = t3 * g2, to4 = t4 * g2;

    float pfo = s_out * focus_w[lane]
              + vo0 * focus_w[64 + lane * 3 + 0]
              + vo1 * focus_w[64 + lane * 3 + 1]
              + vo2 * focus_w[64 + lane * 3 + 2]
              + to0 * focus_w[256 + lane * 5 + 0]
              + to1 * focus_w[256 + lane * 5 + 1]
              + to2 * focus_w[256 + lane * 5 + 2]
              + to3 * focus_w[256 + lane * 5 + 3]
              + to4 * focus_w[256 + lane * 5 + 4];
    #pragma unroll
    for (int off = 32; off > 0; off >>= 1) pfo += __shfl_down(pfo, off);
    if (lane == 0) out_focus[n] = pfo + focus_b[0];

    int fg = flags[n];
    if (fg) {
        float* fe = focus_emb + (size_t)(fg - 1) * FLATDIM;
        fe[lane] = s_out;
        fe[64 + lane * 3 + 0] = vo0;
        fe[64 + lane * 3 + 1] = vo1;
        fe[64 + lane * 3 + 2] = vo2;
        fe[256 + lane * 5 + 0] = to0;
        fe[256 + lane * 5 + 1] = to1;
        fe[256 + lane * 5 + 2] = to2;
        fe[256 + lane * 5 + 3] = to3;
        fe[256 + lane * 5 + 4] = to4;
    }
}

// ---- graph stage: block per graph ----
__global__ __launch_bounds__(256) void graph_kernel(
    const float* __restrict__ focus_emb, const int* __restrict__ target_species,
    const float* __restrict__ species_embed,
    const float* __restrict__ species_w, const float* __restrict__ species_b,
    const float* __restrict__ pos_w, const float* __restrict__ pos_b,
    float* __restrict__ out_species, float* __restrict__ out_pos)
{
    int g = blockIdx.x;
    int tid = threadIdx.x;
    __shared__ float pin[POSIN];
    const float* fe = focus_emb + (size_t)g * FLATDIM;
    for (int i = tid; i < FLATDIM; i += 256) pin[i] = fe[i];
    int tsp = target_species[g];
    if (tid < CC) pin[FLATDIM + tid] = species_embed[tsp * CC + tid];
    __syncthreads();

    if (tid < 5) {
        float a = species_b[tid];
        for (int k = 0; k < FLATDIM; k++) a += pin[k] * species_w[k * 5 + tid];
        out_species[g * 5 + tid] = a;
    }
    for (int o = tid; o < POSOUT; o += 256) {
        float a = pos_b[o];
        for (int k = 0; k < POSIN; k++) a += pin[k] * pos_w[(size_t)k * POSOUT + o];
        out_pos[(size_t)g * POSOUT + o] = a;
    }
}

extern "C" void kernel_launch(void* const* d_in, const int* in_sizes, int n_in,
                              void* d_out, int out_size, void* d_ws, size_t ws_size,
                              hipStream_t stream) {
    const float* positions      = (const float*)d_in[0];
    const int*   species        = (const int*)  d_in[1];
    const int*   senders        = (const int*)  d_in[2];
    const int*   receivers      = (const int*)  d_in[3];
    const int*   n_node         = (const int*)  d_in[4];
    const int*   target_species = (const int*)  d_in[5];
    const float* species_embed  = (const float*)d_in[6];
    const float* node_embed     = (const float*)d_in[7];
    const float* radial_w1      = (const float*)d_in[8];
    const float* radial_w2      = (const float*)d_in[9];
    const float* radial_w3      = (const float*)d_in[10];
    const float* lin_w0         = (const float*)d_in[11];
    const float* lin_w1         = (const float*)d_in[12];
    const float* lin_w2         = (const float*)d_in[13];
    const float* skip_w         = (const float*)d_in[14];
    const float* gate_w         = (const float*)d_in[15];
    const float* focus_w        = (const float*)d_in[16];
    const float* focus_b        = (const float*)d_in[17];
    const float* species_w      = (const float*)d_in[18];
    const float* species_b      = (const float*)d_in[19];
    const float* pos_w          = (const float*)d_in[20];
    const float* pos_b          = (const float*)d_in[21];

    // ws layout: payload[320000*80] f | degree[20000] cursor[20000] flags[20000]
    //            start[20001] edge_list[320000] i | w1t[512] focus_emb[57600] f
    float* ws        = (float*)d_ws;
    float* payload   = ws;
    int*   degree    = (int*)(ws + (size_t)NEDGES * PAYLOAD);
    int*   cursor    = degree + NNODES;
    int*   flags     = cursor + NNODES;
    int*   start     = flags + NNODES;
    int*   edge_list = start + NNODES + 1;
    float* w1t       = (float*)(edge_list + NEDGES);
    float* focus_emb = w1t + 512;

    // zero degree+cursor+flags (contiguous)
    hipMemsetAsync(degree, 0, 3 * NNODES * sizeof(int), stream);

    prep_kernel<<<64, 256, 0, stream>>>(radial_w1, n_node, receivers, w1t, flags, degree);
    scan_kernel<<<1, 1024, 0, stream>>>(degree, start);
    edge_kernel<<<(NEDGES + 255) / 256, 256, 0, stream>>>(
        positions, species, senders, receivers, w1t, radial_w2,
        start, cursor, edge_list, payload);

    float* out       = (float*)d_out;
    float* out_focus = out;
    float* out_spec  = out + NNODES;
    float* out_pos   = out + NNODES + NGRAPHS * 5;

    node_kernel<<<NNODES / 4, 256, 0, stream>>>(
        payload, edge_list, start, species, node_embed, radial_w3,
        lin_w0, lin_w1, lin_w2, skip_w, gate_w, focus_w, focus_b, flags,
        out_focus, focus_emb);

    graph_kernel<<<NGRAPHS, 256, 0, stream>>>(
        focus_emb, target_species, species_embed, species_w, species_b,
        pos_w, pos_b, out_spec, out_pos);
}

// Round 3
// 1096.329 us; speedup vs baseline: 8.5173x; 1.3476x over previous
//
#include <hip/hip_runtime.h>
#include <hip/hip_bf16.h>
#include <math.h>

// ---- problem constants ----
#define NNODES   20000
#define NEDGES   320000
#define NGRAPHS  100
#define CC       64        // LATENT
#define FLATDIM  576       // C*(1+3+5)
#define POSIN    640       // FLAT + C
#define POSOUT   1600      // NRADII*IRRDIM
#define PAYL     200       // bf16: b0[64] b1[64] b2[64] sh[8]  -> 400B row (16B aligned)

__device__ __forceinline__ float silu_f(float x){ return x / (1.0f + __expf(-x)); }
__device__ __forceinline__ float sigm_f(float x){ return 1.0f / (1.0f + __expf(-x)); }
__device__ __forceinline__ unsigned pk_bf16(float lo, float hi){
    __hip_bfloat162 t;
    t.x = __float2bfloat16(lo);
    t.y = __float2bfloat16(hi);
    return *reinterpret_cast<unsigned*>(&t);
}
__device__ __forceinline__ float bf_lo(unsigned u){ return __uint_as_float(u << 16); }
__device__ __forceinline__ float bf_hi(unsigned u){ return __uint_as_float(u & 0xffff0000u); }

// ---- prep: transpose radial_w1 [8][64]->[64][8], radial_w3 [64][192]->[192][64];
//      graph-first flags; degree count ----
__global__ void prep_kernel(const float* __restrict__ w1, const float* __restrict__ w3,
                            const int* __restrict__ n_node,
                            const int* __restrict__ receivers,
                            float* __restrict__ w1t, float* __restrict__ w3t,
                            int* __restrict__ flags, int* __restrict__ degree)
{
    int tid = blockIdx.x * blockDim.x + threadIdx.x;
    int stride = gridDim.x * blockDim.x;
    for (int i = tid; i < 8 * 64; i += stride) {
        int b = i / 64, k = i % 64;
        w1t[k * 8 + b] = w1[i];
    }
    for (int i = tid; i < 64 * 192; i += stride) {
        int k = i / 192, o = i % 192;
        w3t[o * 64 + k] = w3[i];
    }
    for (int e = tid; e < NEDGES; e += stride)
        atomicAdd(&degree[receivers[e]], 1);
    if (tid == 0) {
        int a = 0;
        for (int g = 0; g < NGRAPHS; g++) { flags[a] = g + 1; a += n_node[g]; }
    }
}

// ---- exclusive scan of degree[20000] -> start[20001], single block ----
__global__ __launch_bounds__(1024) void scan_kernel(const int* __restrict__ degree,
                                                    int* __restrict__ start)
{
    __shared__ int partial[1024];
    int t = threadIdx.x;
    int base = t * 20;
    int s = 0;
    int loc[20];
    for (int i = 0; i < 20; i++) {
        int idx = base + i;
        int d = (idx < NNODES) ? degree[idx] : 0;
        loc[i] = s;
        s += d;
    }
    partial[t] = s;
    __syncthreads();
    if (t == 0) {
        int run = 0;
        for (int i = 0; i < 1024; i++) { int x = partial[i]; partial[i] = run; run += x; }
        start[NNODES] = run;
    }
    __syncthreads();
    int off = partial[t];
    for (int i = 0; i < 20; i++) {
        int idx = base + i;
        if (idx < NNODES) start[idx] = off + loc[i];
    }
}

// ---- edge stage: stages 1-3 of the radial MLP + sph; fold sender embed + 1/sqrt(16);
//      write bf16 payload at CSR slot ----
__global__ __launch_bounds__(256) void edge_kernel(
    const float* __restrict__ pos, const int* __restrict__ species,
    const int* __restrict__ senders, const int* __restrict__ receivers,
    const float* __restrict__ node_embed,
    const float* __restrict__ w1t, const float* __restrict__ w2,
    const float* __restrict__ w3t,
    const int* __restrict__ start, int* __restrict__ cursor,
    unsigned* __restrict__ payload)
{
    int e = blockIdx.x * blockDim.x + threadIdx.x;
    if (e >= NEDGES) return;
    int snd = senders[e];
    int rcv = receivers[e];
    int slot = start[rcv] + atomicAdd(&cursor[rcv], 1);

    float dx = pos[rcv * 3 + 0] - pos[snd * 3 + 0];
    float dy = pos[rcv * 3 + 1] - pos[snd * 3 + 1];
    float dz = pos[rcv * 3 + 2] - pos[snd * 3 + 2];
    float r = sqrtf(dx * dx + dy * dy + dz * dz);
    float rinv = 1.0f / (r + 1e-9f);
    float ux = dx * rinv, uy = dy * rinv, uz = dz * rinv;

    const float SQ3 = 1.7320508075688772f;
    const float S15 = 3.872983346207417f;
    const float S5  = 2.2360679774997896f;
    float sh[8];
    sh[0] = SQ3 * ux; sh[1] = SQ3 * uy; sh[2] = SQ3 * uz;
    sh[3] = S15 * ux * uy;
    sh[4] = S15 * uy * uz;
    sh[5] = 0.5f * S5 * (3.0f * uz * uz - 1.0f);
    sh[6] = S15 * ux * uz;
    sh[7] = 0.5f * S15 * (ux * ux - uy * uy);

    const float PI = 3.14159265358979323846f;
    float rc = r * 0.2f;
    float env = 0.5f * (__cosf(PI * fminf(rc, 1.0f)) + 1.0f);
    float scale = 0.6324555320336759f * rinv * env;
    float rb[8];
    #pragma unroll
    for (int b = 0; b < 8; b++) rb[b] = scale * __sinf((float)(b + 1) * PI * rc);

    // stage 2
    float hid2[64];
    #pragma unroll
    for (int c = 0; c < 64; c++) hid2[c] = 0.0f;
    for (int k = 0; k < 64; k++) {
        float a = 0.0f;
        const float* w1c = w1t + k * 8;
        #pragma unroll
        for (int b = 0; b < 8; b++) a += rb[b] * w1c[b];
        float h1 = silu_f(a);
        const float* w2row = w2 + k * 64;
        #pragma unroll
        for (int c = 0; c < 64; c++) hid2[c] += h1 * w2row[c];
    }
    #pragma unroll
    for (int c = 0; c < 64; c++) hid2[c] = silu_f(hid2[c]);

    // stage 3: wts = hid2 @ w3 (two channels per iter), fold hs*0.25, store bf16
    int sp = species[snd];
    const float* hrow = node_embed + sp * 64;
    unsigned* prow = payload + (size_t)slot * (PAYL / 2);   // 100 uints per row

    for (int c2 = 0; c2 < 32; c2++) {
        int ca = 2 * c2, cb = ca + 1;
        const float* pa0 = w3t + ca * 64;
        const float* pb0 = w3t + cb * 64;
        const float* pa1 = w3t + (64 + ca) * 64;
        const float* pb1 = w3t + (64 + cb) * 64;
        const float* pa2 = w3t + (128 + ca) * 64;
        const float* pb2 = w3t + (128 + cb) * 64;
        float a0 = 0, b0 = 0, a1 = 0, b1 = 0, a2 = 0, b2 = 0;
        #pragma unroll
        for (int k = 0; k < 64; k++) {
            float h = hid2[k];
            a0 += h * pa0[k]; b0 += h * pb0[k];
            a1 += h * pa1[k]; b1 += h * pb1[k];
            a2 += h * pa2[k]; b2 += h * pb2[k];
        }
        float ha = hrow[ca] * 0.25f;
        float hb = hrow[cb] * 0.25f;
        prow[c2]      = pk_bf16(a0 * ha, b0 * hb);
        prow[32 + c2] = pk_bf16(a1 * ha, b1 * hb);
        prow[64 + c2] = pk_bf16(a2 * ha, b2 * hb);
    }
    prow[96] = pk_bf16(sh[0], sh[1]);
    prow[97] = pk_bf16(sh[2], sh[3]);
    prow[98] = pk_bf16(sh[4], sh[5]);
    prow[99] = pk_bf16(sh[6], sh[7]);
}

// ---- fused gather + node stage: one wave per node (4 waves/block) ----
__global__ __launch_bounds__(256) void node_kernel(
    const unsigned* __restrict__ payload, const int* __restrict__ start,
    const int* __restrict__ species, const float* __restrict__ node_embed,
    const float* __restrict__ lin_w0, const float* __restrict__ lin_w1,
    const float* __restrict__ lin_w2, const float* __restrict__ skip_w,
    const float* __restrict__ gate_w, const float* __restrict__ focus_w,
    const float* __restrict__ focus_b, const int* __restrict__ flags,
    float* __restrict__ out_focus, float* __restrict__ focus_emb)
{
    int wave = threadIdx.x >> 6;
    int lane = threadIdx.x & 63;
    int n = blockIdx.x * 4 + wave;

    __shared__ float sa[4][9][64];
    __shared__ float hh[4][64];
    __shared__ float ss[4][64];

    float a0 = 0, a1x = 0, a1y = 0, a1z = 0;
    float a2a = 0, a2b = 0, a2c = 0, a2d = 0, a2e = 0;
    int s0 = start[n], s1 = start[n + 1];
    for (int i = s0; i < s1; i++) {
        const unsigned short* p16 = (const unsigned short*)(payload + (size_t)i * (PAYL / 2));
        float b0 = __uint_as_float(((unsigned)p16[lane]) << 16);
        float b1 = __uint_as_float(((unsigned)p16[64 + lane]) << 16);
        float b2 = __uint_as_float(((unsigned)p16[128 + lane]) << 16);
        uint4 sv = *reinterpret_cast<const uint4*>(p16 + 192);
        float sh0 = bf_lo(sv.x), sh1 = bf_hi(sv.x);
        float sh2 = bf_lo(sv.y), sh3 = bf_hi(sv.y);
        float sh4 = bf_lo(sv.z), sh5 = bf_hi(sv.z);
        float sh6 = bf_lo(sv.w), sh7 = bf_hi(sv.w);
        a0  += b0;
        a1x += b1 * sh0; a1y += b1 * sh1; a1z += b1 * sh2;
        a2a += b2 * sh3; a2b += b2 * sh4; a2c += b2 * sh5;
        a2d += b2 * sh6; a2e += b2 * sh7;
    }

    // ---- node stage (wave-local LDS) ----
    sa[wave][0][lane] = a0;
    sa[wave][1][lane] = a1x; sa[wave][2][lane] = a1y; sa[wave][3][lane] = a1z;
    sa[wave][4][lane] = a2a; sa[wave][5][lane] = a2b; sa[wave][6][lane] = a2c;
    sa[wave][7][lane] = a2d; sa[wave][8][lane] = a2e;
    int spn = species[n];
    hh[wave][lane] = node_embed[spn * 64 + lane];

    float s = 0.0f;
    const float* skipb = skip_w + spn * 4096;
    for (int c = 0; c < 64; c++)
        s += sa[wave][0][c] * lin_w0[c * 64 + lane] + hh[wave][c] * skipb[c * 64 + lane];

    float v0 = 0, v1 = 0, v2 = 0, t0 = 0, t1 = 0, t2 = 0, t3 = 0, t4 = 0;
    for (int c = 0; c < 64; c++) {
        float wa = lin_w1[c * 64 + lane];
        v0 += sa[wave][1][c] * wa; v1 += sa[wave][2][c] * wa; v2 += sa[wave][3][c] * wa;
        float wb = lin_w2[c * 64 + lane];
        t0 += sa[wave][4][c] * wb; t1 += sa[wave][5][c] * wb; t2 += sa[wave][6][c] * wb;
        t3 += sa[wave][7][c] * wb; t4 += sa[wave][8][c] * wb;
    }

    ss[wave][lane] = s;
    float g1a = 0.0f, g2a = 0.0f;
    for (int c = 0; c < 64; c++) {
        float sc = ss[wave][c];
        g1a += sc * gate_w[c * 128 + lane];
        g2a += sc * gate_w[c * 128 + 64 + lane];
    }
    float g1 = sigm_f(g1a), g2 = sigm_f(g2a);
    float s_out = s * sigm_f(s);
    float vo0 = v0 * g1, vo1 = v1 * g1, vo2 = v2 * g1;
    float to0 = t0 * g2, to1 = t1 * g2, to2 = t2 * g2, to3 = t3 * g2, to4 = t4 * g2;

    float pfo = s_out * focus_w[lane]
              + vo0 * focus_w[64 + lane * 3 + 0]
              + vo1 * focus_w[64 + lane * 3 + 1]
              + vo2 * focus_w[64 + lane * 3 + 2]
              + to0 * focus_w[256 + lane * 5 + 0]
              + to1 * focus_w[256 + lane * 5 + 1]
              + to2 * focus_w[256 + lane * 5 + 2]
              + to3 * focus_w[256 + lane * 5 + 3]
              + to4 * focus_w[256 + lane * 5 + 4];
    #pragma unroll
    for (int off = 32; off > 0; off >>= 1) pfo += __shfl_down(pfo, off);
    if (lane == 0) out_focus[n] = pfo + focus_b[0];

    int fg = flags[n];
    if (fg) {
        float* fe = focus_emb + (size_t)(fg - 1) * FLATDIM;
        fe[lane] = s_out;
        fe[64 + lane * 3 + 0] = vo0;
        fe[64 + lane * 3 + 1] = vo1;
        fe[64 + lane * 3 + 2] = vo2;
        fe[256 + lane * 5 + 0] = to0;
        fe[256 + lane * 5 + 1] = to1;
        fe[256 + lane * 5 + 2] = to2;
        fe[256 + lane * 5 + 3] = to3;
        fe[256 + lane * 5 + 4] = to4;
    }
}

// ---- graph stage: block per graph ----
__global__ __launch_bounds__(256) void graph_kernel(
    const float* __restrict__ focus_emb, const int* __restrict__ target_species,
    const float* __restrict__ species_embed,
    const float* __restrict__ species_w, const float* __restrict__ species_b,
    const float* __restrict__ pos_w, const float* __restrict__ pos_b,
    float* __restrict__ out_species, float* __restrict__ out_pos)
{
    int g = blockIdx.x;
    int tid = threadIdx.x;
    __shared__ float pin[POSIN];
    const float* fe = focus_emb + (size_t)g * FLATDIM;
    for (int i = tid; i < FLATDIM; i += 256) pin[i] = fe[i];
    int tsp = target_species[g];
    if (tid < CC) pin[FLATDIM + tid] = species_embed[tsp * CC + tid];
    __syncthreads();

    if (tid < 5) {
        float a = species_b[tid];
        for (int k = 0; k < FLATDIM; k++) a += pin[k] * species_w[k * 5 + tid];
        out_species[g * 5 + tid] = a;
    }
    for (int o = tid; o < POSOUT; o += 256) {
        float a = pos_b[o];
        for (int k = 0; k < POSIN; k++) a += pin[k] * pos_w[(size_t)k * POSOUT + o];
        out_pos[(size_t)g * POSOUT + o] = a;
    }
}

extern "C" void kernel_launch(void* const* d_in, const int* in_sizes, int n_in,
                              void* d_out, int out_size, void* d_ws, size_t ws_size,
                              hipStream_t stream) {
    const float* positions      = (const float*)d_in[0];
    const int*   species        = (const int*)  d_in[1];
    const int*   senders        = (const int*)  d_in[2];
    const int*   receivers      = (const int*)  d_in[3];
    const int*   n_node         = (const int*)  d_in[4];
    const int*   target_species = (const int*)  d_in[5];
    const float* species_embed  = (const float*)d_in[6];
    const float* node_embed     = (const float*)d_in[7];
    const float* radial_w1      = (const float*)d_in[8];
    const float* radial_w2      = (const float*)d_in[9];
    const float* radial_w3      = (const float*)d_in[10];
    const float* lin_w0         = (const float*)d_in[11];
    const float* lin_w1         = (const float*)d_in[12];
    const float* lin_w2         = (const float*)d_in[13];
    const float* skip_w         = (const float*)d_in[14];
    const float* gate_w         = (const float*)d_in[15];
    const float* focus_w        = (const float*)d_in[16];
    const float* focus_b        = (const float*)d_in[17];
    const float* species_w      = (const float*)d_in[18];
    const float* species_b      = (const float*)d_in[19];
    const float* pos_w          = (const float*)d_in[20];
    const float* pos_b          = (const float*)d_in[21];

    // ws layout: payload bf16 [320000*200] (= 320000*100 uints, 128MB)
    //          | degree[20000] cursor[20000] flags[20000] start[20001] (ints)
    //          | w1t[512] w3t[12288] focus_emb[57600] (floats)
    unsigned* payload = (unsigned*)d_ws;
    int* degree = (int*)(payload + (size_t)NEDGES * (PAYL / 2));
    int* cursor = degree + NNODES;
    int* flags  = cursor + NNODES;
    int* start  = flags + NNODES;
    float* w1t  = (float*)(start + NNODES + 1);
    float* w3t  = w1t + 512;
    float* focus_emb = w3t + 12288;

    hipMemsetAsync(degree, 0, 3 * NNODES * sizeof(int), stream);

    prep_kernel<<<128, 256, 0, stream>>>(radial_w1, radial_w3, n_node, receivers,
                                         w1t, w3t, flags, degree);
    scan_kernel<<<1, 1024, 0, stream>>>(degree, start);
    edge_kernel<<<(NEDGES + 255) / 256, 256, 0, stream>>>(
        positions, species, senders, receivers, node_embed, w1t, radial_w2, w3t,
        start, cursor, payload);

    float* out       = (float*)d_out;
    float* out_focus = out;
    float* out_spec  = out + NNODES;
    float* out_pos   = out + NNODES + NGRAPHS * 5;

    node_kernel<<<NNODES / 4, 256, 0, stream>>>(
        payload, start, species, node_embed,
        lin_w0, lin_w1, lin_w2, skip_w, gate_w, focus_w, focus_b, flags,
        out_focus, focus_emb);

    graph_kernel<<<NGRAPHS, 256, 0, stream>>>(
        focus_emb, target_species, species_embed, species_w, species_b,
        pos_w, pos_b, out_spec, out_pos);
}

// Round 4
// 816.558 us; speedup vs baseline: 11.4355x; 1.3426x over previous
//
#include <hip/hip_runtime.h>
#include <hip/hip_bf16.h>
#include <math.h>

// ---- problem constants ----
#define NNODES   20000
#define NEDGES   320000
#define NGRAPHS  100
#define CC       64        // LATENT
#define FLATDIM  576       // C*(1+3+5)
#define POSIN    640       // FLAT + C
#define POSOUT   1600      // NRADII*IRRDIM
#define PAYL     200       // bf16: b0[64] b1[64] b2[64] sh[8]  -> 400B row (16B aligned)

__device__ __forceinline__ float silu_f(float x){ return x / (1.0f + __expf(-x)); }
__device__ __forceinline__ float sigm_f(float x){ return 1.0f / (1.0f + __expf(-x)); }
__device__ __forceinline__ unsigned pk_bf16(float lo, float hi){
    __hip_bfloat162 t;
    t.x = __float2bfloat16(lo);
    t.y = __float2bfloat16(hi);
    return *reinterpret_cast<unsigned*>(&t);
}
__device__ __forceinline__ float bf_lo(unsigned u){ return __uint_as_float(u << 16); }
__device__ __forceinline__ float bf_hi(unsigned u){ return __uint_as_float(u & 0xffff0000u); }

// ---- prep ----
__global__ void prep_kernel(const float* __restrict__ w1, const float* __restrict__ w3,
                            const int* __restrict__ n_node,
                            const int* __restrict__ receivers,
                            float* __restrict__ w1t, float* __restrict__ w3t,
                            int* __restrict__ flags, int* __restrict__ degree)
{
    int tid = blockIdx.x * blockDim.x + threadIdx.x;
    int stride = gridDim.x * blockDim.x;
    for (int i = tid; i < 8 * 64; i += stride) {
        int b = i / 64, k = i % 64;
        w1t[k * 8 + b] = w1[i];
    }
    for (int i = tid; i < 64 * 192; i += stride) {
        int k = i / 192, o = i % 192;
        w3t[o * 64 + k] = w3[i];
    }
    for (int e = tid; e < NEDGES; e += stride)
        atomicAdd(&degree[receivers[e]], 1);
    if (tid == 0) {
        int a = 0;
        for (int g = 0; g < NGRAPHS; g++) { flags[a] = g + 1; a += n_node[g]; }
    }
}

// ---- exclusive scan of degree[20000] -> start[20001], single block ----
__global__ __launch_bounds__(1024) void scan_kernel(const int* __restrict__ degree,
                                                    int* __restrict__ start)
{
    __shared__ int partial[1024];
    int t = threadIdx.x;
    int base = t * 20;
    int s = 0;
    int loc[20];
    for (int i = 0; i < 20; i++) {
        int idx = base + i;
        int d = (idx < NNODES) ? degree[idx] : 0;
        loc[i] = s;
        s += d;
    }
    partial[t] = s;
    __syncthreads();
    if (t == 0) {
        int run = 0;
        for (int i = 0; i < 1024; i++) { int x = partial[i]; partial[i] = run; run += x; }
        start[NNODES] = run;
    }
    __syncthreads();
    int off = partial[t];
    for (int i = 0; i < 20; i++) {
        int idx = base + i;
        if (idx < NNODES) start[idx] = off + loc[i];
    }
}

// Manual-SROA helpers: hid2 lives in 16 NAMED float4s (ha0..ha15) so every
// access is compile-time-indexed -> guaranteed register residency (rule #20).
#define HID_LIST ha0,ha1,ha2,ha3,ha4,ha5,ha6,ha7,ha8,ha9,ha10,ha11,ha12,ha13,ha14,ha15
#define FMA1(h,q,i)  h.x += s1v*q[i].x; h.y += s1v*q[i].y; h.z += s1v*q[i].z; h.w += s1v*q[i].w;
#define FMA16(q) FMA1(ha0,q,0) FMA1(ha1,q,1) FMA1(ha2,q,2) FMA1(ha3,q,3) \
                 FMA1(ha4,q,4) FMA1(ha5,q,5) FMA1(ha6,q,6) FMA1(ha7,q,7) \
                 FMA1(ha8,q,8) FMA1(ha9,q,9) FMA1(ha10,q,10) FMA1(ha11,q,11) \
                 FMA1(ha12,q,12) FMA1(ha13,q,13) FMA1(ha14,q,14) FMA1(ha15,q,15)
#define SIL1(h) h.x = silu_f(h.x); h.y = silu_f(h.y); h.z = silu_f(h.z); h.w = silu_f(h.w);
#define SIL16() SIL1(ha0) SIL1(ha1) SIL1(ha2) SIL1(ha3) SIL1(ha4) SIL1(ha5) SIL1(ha6) SIL1(ha7) \
                SIL1(ha8) SIL1(ha9) SIL1(ha10) SIL1(ha11) SIL1(ha12) SIL1(ha13) SIL1(ha14) SIL1(ha15)
#define DOT1(acc,q,i,h) acc += h.x*q[i].x + h.y*q[i].y + h.z*q[i].z + h.w*q[i].w;
#define DOT16(acc,q) DOT1(acc,q,0,ha0) DOT1(acc,q,1,ha1) DOT1(acc,q,2,ha2) DOT1(acc,q,3,ha3) \
                     DOT1(acc,q,4,ha4) DOT1(acc,q,5,ha5) DOT1(acc,q,6,ha6) DOT1(acc,q,7,ha7) \
                     DOT1(acc,q,8,ha8) DOT1(acc,q,9,ha9) DOT1(acc,q,10,ha10) DOT1(acc,q,11,ha11) \
                     DOT1(acc,q,12,ha12) DOT1(acc,q,13,ha13) DOT1(acc,q,14,ha14) DOT1(acc,q,15,ha15)

// ---- edge stage: stages 1-3 of the radial MLP + sph; fold sender embed + 1/sqrt(16);
//      write bf16 payload at CSR slot ----
__global__ __launch_bounds__(256) void edge_kernel(
    const float* __restrict__ pos, const int* __restrict__ species,
    const int* __restrict__ senders, const int* __restrict__ receivers,
    const float* __restrict__ node_embed,
    const float* __restrict__ w1t, const float* __restrict__ w2,
    const float* __restrict__ w3t,
    const int* __restrict__ start, int* __restrict__ cursor,
    unsigned* __restrict__ payload)
{
    int e = blockIdx.x * blockDim.x + threadIdx.x;
    if (e >= NEDGES) return;
    int snd = senders[e];
    int rcv = receivers[e];
    int slot = start[rcv] + atomicAdd(&cursor[rcv], 1);

    float dx = pos[rcv * 3 + 0] - pos[snd * 3 + 0];
    float dy = pos[rcv * 3 + 1] - pos[snd * 3 + 1];
    float dz = pos[rcv * 3 + 2] - pos[snd * 3 + 2];
    float r = sqrtf(dx * dx + dy * dy + dz * dz);
    float rinv = 1.0f / (r + 1e-9f);
    float ux = dx * rinv, uy = dy * rinv, uz = dz * rinv;

    const float SQ3 = 1.7320508075688772f;
    const float S15 = 3.872983346207417f;
    const float S5  = 2.2360679774997896f;
    float sh0 = SQ3 * ux, sh1 = SQ3 * uy, sh2 = SQ3 * uz;
    float sh3 = S15 * ux * uy;
    float sh4 = S15 * uy * uz;
    float sh5 = 0.5f * S5 * (3.0f * uz * uz - 1.0f);
    float sh6 = S15 * ux * uz;
    float sh7 = 0.5f * S15 * (ux * ux - uy * uy);

    const float PI = 3.14159265358979323846f;
    float rc = r * 0.2f;
    float env = 0.5f * (__cosf(PI * fminf(rc, 1.0f)) + 1.0f);
    float scale = 0.6324555320336759f * rinv * env;
    float rb0 = scale * __sinf(1.0f * PI * rc);
    float rb1 = scale * __sinf(2.0f * PI * rc);
    float rb2 = scale * __sinf(3.0f * PI * rc);
    float rb3 = scale * __sinf(4.0f * PI * rc);
    float rb4 = scale * __sinf(5.0f * PI * rc);
    float rb5 = scale * __sinf(6.0f * PI * rc);
    float rb6 = scale * __sinf(7.0f * PI * rc);
    float rb7 = scale * __sinf(8.0f * PI * rc);

    // stage 2: hid2 in 16 named float4s
    float4 ha0 = {0,0,0,0}, ha1 = {0,0,0,0}, ha2 = {0,0,0,0}, ha3 = {0,0,0,0};
    float4 ha4 = {0,0,0,0}, ha5 = {0,0,0,0}, ha6 = {0,0,0,0}, ha7 = {0,0,0,0};
    float4 ha8 = {0,0,0,0}, ha9 = {0,0,0,0}, ha10 = {0,0,0,0}, ha11 = {0,0,0,0};
    float4 ha12 = {0,0,0,0}, ha13 = {0,0,0,0}, ha14 = {0,0,0,0}, ha15 = {0,0,0,0};
    for (int k = 0; k < 64; k++) {
        const float* w1c = w1t + k * 8;
        float a = rb0 * w1c[0] + rb1 * w1c[1] + rb2 * w1c[2] + rb3 * w1c[3]
                + rb4 * w1c[4] + rb5 * w1c[5] + rb6 * w1c[6] + rb7 * w1c[7];
        float s1v = silu_f(a);
        const float4* q = reinterpret_cast<const float4*>(w2 + k * 64);
        FMA16(q)
    }
    SIL16()

    // stage 3: wts = hid2 @ w3 (via w3t rows), fold hs*0.25, store bf16
    int sp = species[snd];
    const float* hrow = node_embed + sp * 64;
    unsigned* prow = payload + (size_t)slot * (PAYL / 2);   // 100 uints per row

    for (int c2 = 0; c2 < 32; c2++) {
        int ca = 2 * c2, cb = ca + 1;
        const float4* qa0 = reinterpret_cast<const float4*>(w3t + ca * 64);
        const float4* qb0 = reinterpret_cast<const float4*>(w3t + cb * 64);
        const float4* qa1 = reinterpret_cast<const float4*>(w3t + (64 + ca) * 64);
        const float4* qb1 = reinterpret_cast<const float4*>(w3t + (64 + cb) * 64);
        const float4* qa2 = reinterpret_cast<const float4*>(w3t + (128 + ca) * 64);
        const float4* qb2 = reinterpret_cast<const float4*>(w3t + (128 + cb) * 64);
        float a0 = 0, b0 = 0, a1 = 0, b1 = 0, a2 = 0, b2 = 0;
        DOT16(a0, qa0) DOT16(b0, qb0)
        DOT16(a1, qa1) DOT16(b1, qb1)
        DOT16(a2, qa2) DOT16(b2, qb2)
        float haf = hrow[ca] * 0.25f;
        float hbf = hrow[cb] * 0.25f;
        prow[c2]      = pk_bf16(a0 * haf, b0 * hbf);
        prow[32 + c2] = pk_bf16(a1 * haf, b1 * hbf);
        prow[64 + c2] = pk_bf16(a2 * haf, b2 * hbf);
    }
    prow[96] = pk_bf16(sh0, sh1);
    prow[97] = pk_bf16(sh2, sh3);
    prow[98] = pk_bf16(sh4, sh5);
    prow[99] = pk_bf16(sh6, sh7);
}

// ---- fused gather + node stage: one wave per node (4 waves/block) ----
__global__ __launch_bounds__(256, 4) void node_kernel(
    const unsigned* __restrict__ payload, const int* __restrict__ start,
    const int* __restrict__ species, const float* __restrict__ node_embed,
    const float* __restrict__ lin_w0, const float* __restrict__ lin_w1,
    const float* __restrict__ lin_w2, const float* __restrict__ skip_w,
    const float* __restrict__ gate_w, const float* __restrict__ focus_w,
    const float* __restrict__ focus_b, const int* __restrict__ flags,
    float* __restrict__ out_focus, float* __restrict__ focus_emb)
{
    int wave = threadIdx.x >> 6;
    int lane = threadIdx.x & 63;
    int n = blockIdx.x * 4 + wave;

    __shared__ float sa[4][9][64];
    __shared__ float hh[4][64];
    __shared__ float ss[4][64];

    // gather: dual accumulator sets to break the FMA dependency chain
    float a0 = 0, a1x = 0, a1y = 0, a1z = 0;
    float a2a = 0, a2b = 0, a2c = 0, a2d = 0, a2e = 0;
    float c0 = 0, c1x = 0, c1y = 0, c1z = 0;
    float c2a = 0, c2b = 0, c2c = 0, c2d = 0, c2e = 0;
    int s0 = start[n], s1 = start[n + 1];
    int i = s0;
    for (; i + 1 < s1; i += 2) {
        const unsigned short* pA = (const unsigned short*)(payload + (size_t)i * (PAYL / 2));
        const unsigned short* pB = (const unsigned short*)(payload + (size_t)(i + 1) * (PAYL / 2));
        float Ab0 = __uint_as_float(((unsigned)pA[lane]) << 16);
        float Ab1 = __uint_as_float(((unsigned)pA[64 + lane]) << 16);
        float Ab2 = __uint_as_float(((unsigned)pA[128 + lane]) << 16);
        uint4 Asv = *reinterpret_cast<const uint4*>(pA + 192);
        float Bb0 = __uint_as_float(((unsigned)pB[lane]) << 16);
        float Bb1 = __uint_as_float(((unsigned)pB[64 + lane]) << 16);
        float Bb2 = __uint_as_float(((unsigned)pB[128 + lane]) << 16);
        uint4 Bsv = *reinterpret_cast<const uint4*>(pB + 192);
        a0  += Ab0;
        a1x += Ab1 * bf_lo(Asv.x); a1y += Ab1 * bf_hi(Asv.x); a1z += Ab1 * bf_lo(Asv.y);
        a2a += Ab2 * bf_hi(Asv.y); a2b += Ab2 * bf_lo(Asv.z); a2c += Ab2 * bf_hi(Asv.z);
        a2d += Ab2 * bf_lo(Asv.w); a2e += Ab2 * bf_hi(Asv.w);
        c0  += Bb0;
        c1x += Bb1 * bf_lo(Bsv.x); c1y += Bb1 * bf_hi(Bsv.x); c1z += Bb1 * bf_lo(Bsv.y);
        c2a += Bb2 * bf_hi(Bsv.y); c2b += Bb2 * bf_lo(Bsv.z); c2c += Bb2 * bf_hi(Bsv.z);
        c2d += Bb2 * bf_lo(Bsv.w); c2e += Bb2 * bf_hi(Bsv.w);
    }
    if (i < s1) {
        const unsigned short* pA = (const unsigned short*)(payload + (size_t)i * (PAYL / 2));
        float Ab0 = __uint_as_float(((unsigned)pA[lane]) << 16);
        float Ab1 = __uint_as_float(((unsigned)pA[64 + lane]) << 16);
        float Ab2 = __uint_as_float(((unsigned)pA[128 + lane]) << 16);
        uint4 Asv = *reinterpret_cast<const uint4*>(pA + 192);
        a0  += Ab0;
        a1x += Ab1 * bf_lo(Asv.x); a1y += Ab1 * bf_hi(Asv.x); a1z += Ab1 * bf_lo(Asv.y);
        a2a += Ab2 * bf_hi(Asv.y); a2b += Ab2 * bf_lo(Asv.z); a2c += Ab2 * bf_hi(Asv.z);
        a2d += Ab2 * bf_lo(Asv.w); a2e += Ab2 * bf_hi(Asv.w);
    }
    a0 += c0; a1x += c1x; a1y += c1y; a1z += c1z;
    a2a += c2a; a2b += c2b; a2c += c2c; a2d += c2d; a2e += c2e;

    // ---- node stage (wave-local LDS) ----
    sa[wave][0][lane] = a0;
    sa[wave][1][lane] = a1x; sa[wave][2][lane] = a1y; sa[wave][3][lane] = a1z;
    sa[wave][4][lane] = a2a; sa[wave][5][lane] = a2b; sa[wave][6][lane] = a2c;
    sa[wave][7][lane] = a2d; sa[wave][8][lane] = a2e;
    int spn = species[n];
    hh[wave][lane] = node_embed[spn * 64 + lane];

    float s = 0.0f;
    const float* skipb = skip_w + spn * 4096;
    #pragma unroll 8
    for (int c = 0; c < 64; c++)
        s += sa[wave][0][c] * lin_w0[c * 64 + lane] + hh[wave][c] * skipb[c * 64 + lane];

    float v0 = 0, v1 = 0, v2 = 0, t0 = 0, t1 = 0, t2 = 0, t3 = 0, t4 = 0;
    #pragma unroll 8
    for (int c = 0; c < 64; c++) {
        float wa = lin_w1[c * 64 + lane];
        v0 += sa[wave][1][c] * wa; v1 += sa[wave][2][c] * wa; v2 += sa[wave][3][c] * wa;
        float wb = lin_w2[c * 64 + lane];
        t0 += sa[wave][4][c] * wb; t1 += sa[wave][5][c] * wb; t2 += sa[wave][6][c] * wb;
        t3 += sa[wave][7][c] * wb; t4 += sa[wave][8][c] * wb;
    }

    ss[wave][lane] = s;
    float g1a = 0.0f, g2a = 0.0f;
    #pragma unroll 8
    for (int c = 0; c < 64; c++) {
        float sc = ss[wave][c];
        g1a += sc * gate_w[c * 128 + lane];
        g2a += sc * gate_w[c * 128 + 64 + lane];
    }
    float g1 = sigm_f(g1a), g2 = sigm_f(g2a);
    float s_out = s * sigm_f(s);
    float vo0 = v0 * g1, vo1 = v1 * g1, vo2 = v2 * g1;
    float to0 = t0 * g2, to1 = t1 * g2, to2 = t2 * g2, to3 = t3 * g2, to4 = t4 * g2;

    float pfo = s_out * focus_w[lane]
              + vo0 * focus_w[64 + lane * 3 + 0]
              + vo1 * focus_w[64 + lane * 3 + 1]
              + vo2 * focus_w[64 + lane * 3 + 2]
              + to0 * focus_w[256 + lane * 5 + 0]
              + to1 * focus_w[256 + lane * 5 + 1]
              + to2 * focus_w[256 + lane * 5 + 2]
              + to3 * focus_w[256 + lane * 5 + 3]
              + to4 * focus_w[256 + lane * 5 + 4];
    #pragma unroll
    for (int off = 32; off > 0; off >>= 1) pfo += __shfl_down(pfo, off);
    if (lane == 0) out_focus[n] = pfo + focus_b[0];

    int fg = flags[n];
    if (fg) {
        float* fe = focus_emb + (size_t)(fg - 1) * FLATDIM;
        fe[lane] = s_out;
        fe[64 + lane * 3 + 0] = vo0;
        fe[64 + lane * 3 + 1] = vo1;
        fe[64 + lane * 3 + 2] = vo2;
        fe[256 + lane * 5 + 0] = to0;
        fe[256 + lane * 5 + 1] = to1;
        fe[256 + lane * 5 + 2] = to2;
        fe[256 + lane * 5 + 3] = to3;
        fe[256 + lane * 5 + 4] = to4;
    }
}

// ---- graph stage: block per graph ----
__global__ __launch_bounds__(256) void graph_kernel(
    const float* __restrict__ focus_emb, const int* __restrict__ target_species,
    const float* __restrict__ species_embed,
    const float* __restrict__ species_w, const float* __restrict__ species_b,
    const float* __restrict__ pos_w, const float* __restrict__ pos_b,
    float* __restrict__ out_species, float* __restrict__ out_pos)
{
    int g = blockIdx.x;
    int tid = threadIdx.x;
    __shared__ float pin[POSIN];
    const float* fe = focus_emb + (size_t)g * FLATDIM;
    for (int i = tid; i < FLATDIM; i += 256) pin[i] = fe[i];
    int tsp = target_species[g];
    if (tid < CC) pin[FLATDIM + tid] = species_embed[tsp * CC + tid];
    __syncthreads();

    if (tid < 5) {
        float a = species_b[tid];
        for (int k = 0; k < FLATDIM; k++) a += pin[k] * species_w[k * 5 + tid];
        out_species[g * 5 + tid] = a;
    }
    for (int o = tid; o < POSOUT; o += 256) {
        float a = pos_b[o];
        #pragma unroll 8
        for (int k = 0; k < POSIN; k++) a += pin[k] * pos_w[(size_t)k * POSOUT + o];
        out_pos[(size_t)g * POSOUT + o] = a;
    }
}

extern "C" void kernel_launch(void* const* d_in, const int* in_sizes, int n_in,
                              void* d_out, int out_size, void* d_ws, size_t ws_size,
                              hipStream_t stream) {
    const float* positions      = (const float*)d_in[0];
    const int*   species        = (const int*)  d_in[1];
    const int*   senders        = (const int*)  d_in[2];
    const int*   receivers      = (const int*)  d_in[3];
    const int*   n_node         = (const int*)  d_in[4];
    const int*   target_species = (const int*)  d_in[5];
    const float* species_embed  = (const float*)d_in[6];
    const float* node_embed     = (const float*)d_in[7];
    const float* radial_w1      = (const float*)d_in[8];
    const float* radial_w2      = (const float*)d_in[9];
    const float* radial_w3      = (const float*)d_in[10];
    const float* lin_w0         = (const float*)d_in[11];
    const float* lin_w1         = (const float*)d_in[12];
    const float* lin_w2         = (const float*)d_in[13];
    const float* skip_w         = (const float*)d_in[14];
    const float* gate_w         = (const float*)d_in[15];
    const float* focus_w        = (const float*)d_in[16];
    const float* focus_b        = (const float*)d_in[17];
    const float* species_w      = (const float*)d_in[18];
    const float* species_b      = (const float*)d_in[19];
    const float* pos_w          = (const float*)d_in[20];
    const float* pos_b          = (const float*)d_in[21];

    // ws layout: payload bf16 [320000*200] (= 320000*100 uints, 128MB)
    //          | degree[20000] cursor[20000] flags[20000] start[20001] (ints)
    //          | w1t[512] w3t[12288] focus_emb[57600] (floats)
    unsigned* payload = (unsigned*)d_ws;
    int* degree = (int*)(payload + (size_t)NEDGES * (PAYL / 2));
    int* cursor = degree + NNODES;
    int* flags  = cursor + NNODES;
    int* start  = flags + NNODES;
    float* w1t  = (float*)(start + NNODES + 1);
    float* w3t  = w1t + 512;
    float* focus_emb = w3t + 12288;

    hipMemsetAsync(degree, 0, 3 * NNODES * sizeof(int), stream);

    prep_kernel<<<128, 256, 0, stream>>>(radial_w1, radial_w3, n_node, receivers,
                                         w1t, w3t, flags, degree);
    scan_kernel<<<1, 1024, 0, stream>>>(degree, start);
    edge_kernel<<<(NEDGES + 255) / 256, 256, 0, stream>>>(
        positions, species, senders, receivers, node_embed, w1t, radial_w2, w3t,
        start, cursor, payload);

    float* out       = (float*)d_out;
    float* out_focus = out;
    float* out_spec  = out + NNODES;
    float* out_pos   = out + NNODES + NGRAPHS * 5;

    node_kernel<<<NNODES / 4, 256, 0, stream>>>(
        payload, start, species, node_embed,
        lin_w0, lin_w1, lin_w2, skip_w, gate_w, focus_w, focus_b, flags,
        out_focus, focus_emb);

    graph_kernel<<<NGRAPHS, 256, 0, stream>>>(
        focus_emb, target_species, species_embed, species_w, species_b,
        pos_w, pos_b, out_spec, out_pos);
}